// Round 6
// baseline (196.952 us; speedup 1.0000x reference)
//
#include <hip/hip_runtime.h>

// Wavelet cascade (db4, 4 levels, circular) on [B=64, L=512, D=256] f32.
// Sparse view: filter[j][m, (m - 2^j i) mod L] = wav[i]  -> 8-tap dilated
// circular convolution per level; full 4-level cascade done in LDS.
// Output: [B, 5, L, D] f32 = {w_0..w_3 (detail), v_3 (approx)}.
//
// Round-5 change: NONTEMPORAL STORES for all output writes.
// Evidence: round-4 timed 191.6us but profiled run <99us (kernel absent from
// top-5; rocprof drains between dispatches). The harness's 655 MB 0xAA poison
// fill leaves ~256 MB dirty lines in L3/L2; ordinary write-back stores
// allocate in L2/L3 and force-evict that poison inside our timing window
// (round-1: WRITE 390 MB ~= ours 168 + poison ~220; FETCH excess ~128 MB =
// write-allocate fetches). nt stores stream without allocating -> decouple.

typedef float f4 __attribute__((ext_vector_type(4)));

#define WL  512   // signal length
#define WD  256   // feature dim
#define WTD 32    // d-tile per workgroup
#define WNT 512   // threads per block (8 waves)
#define PS  40    // padded LDS row stride in floats (160 B)

__global__ __launch_bounds__(WNT, 4)
void wavelet_cascade_kernel(const float* __restrict__ x,
                            const float* __restrict__ hfil,   // w_dec_filter [4,512,512]
                            const float* __restrict__ gfil,   // v_dec_filter [4,512,512]
                            float* __restrict__ out) {
    __shared__ float buf[WL * PS];   // 80 KB -> 2 blocks/CU (160 KiB exactly)

    const int blk = (int)blockIdx.x;
    const int b   = blk & 63;          // same-b tiles: blk mod 8 == b mod 8 -> same XCD
    const int d0  = (blk >> 6) * WTD;  // 0..7 tile
    const int t   = (int)threadIdx.x;

    // ---- stage x[b, :, d0:d0+32] -> LDS (16B, nontemporal, coalesced) ----
    {
        const f4* src = reinterpret_cast<const f4*>(x + (size_t)b * WL * WD + d0);
#pragma unroll
        for (int k = 0; k < 8; ++k) {
            const int idx = t + k * WNT;
            const int l = idx >> 3;          // 8 f4 per row
            const int q = idx & 7;
            f4 v = __builtin_nontemporal_load(&src[l * (WD / 4) + q]);
            *reinterpret_cast<f4*>(&buf[l * PS + q * 4]) = v;
        }
    }
    __syncthreads();

    const int q  = t & 7;         // f4-column within the 32-wide d-tile
    const int l0 = t >> 3;        // 0..63
    float* outB = out + (size_t)b * 5 * WL * WD + d0 + q * 4;

    f4 vreg[8];                   // v values held in registers between barriers

#pragma unroll
    for (int j = 0; j < 4; ++j) {           // level (compile-time)
        // taps: filter[j][0, (0 - 2^j i) mod L] = wav[i]
        float h[8], g[8];
#pragma unroll
        for (int i = 0; i < 8; ++i) {
            const int off = (WL - (i << j)) & (WL - 1);   // i=0 -> 0
            h[i] = hfil[j * WL * WL + off];
            g[i] = gfil[j * WL * WL + off];
        }

#pragma unroll
        for (int k = 0; k < 8; ++k) {
            const int l = l0 + k * 64;
            f4 wa = {0.f, 0.f, 0.f, 0.f};
            f4 va = {0.f, 0.f, 0.f, 0.f};
#pragma unroll
            for (int i = 0; i < 8; ++i) {
                const int row = (l - (i << j)) & (WL - 1);
                const f4 val = *reinterpret_cast<const f4*>(&buf[row * PS + q * 4]);
                wa += h[i] * val;    // vector fma
                va += g[i] * val;
            }
            __builtin_nontemporal_store(wa, reinterpret_cast<f4*>(&outB[((size_t)j * WL + l) * WD]));
            if (j == 3) {
                __builtin_nontemporal_store(va, reinterpret_cast<f4*>(&outB[((size_t)4 * WL + l) * WD]));
            } else {
                vreg[k] = va;
            }
        }

        if (j < 3) {
            __syncthreads();   // all reads of buf done
#pragma unroll
            for (int k = 0; k < 8; ++k) {
                *reinterpret_cast<f4*>(&buf[(l0 + k * 64) * PS + q * 4]) = vreg[k];
            }
            __syncthreads();   // buf now holds v_j
        }
    }
}

extern "C" void kernel_launch(void* const* d_in, const int* in_sizes, int n_in,
                              void* d_out, int out_size, void* d_ws, size_t ws_size,
                              hipStream_t stream) {
    const float* x    = (const float*)d_in[0];
    const float* wfil = (const float*)d_in[1];   // w_dec_filter (detail, hi-pass)
    const float* vfil = (const float*)d_in[2];   // v_dec_filter (approx, lo-pass)
    float* out = (float*)d_out;

    wavelet_cascade_kernel<<<dim3(64 * 8), dim3(WNT), 0, stream>>>(x, wfil, vfil, out);
}

// Round 7
// 190.933 us; speedup vs baseline: 1.0315x; 1.0315x over previous
//
#include <hip/hip_runtime.h>

// Wavelet cascade (db4, 4 levels, circular) on [B=64, L=512, D=256] f32.
// Sparse view: filter[j][m, (m - 2^j i) mod L] = wav[i]  -> 8-tap dilated
// circular convolution per level; full 4-level cascade done in LDS.
// Output: [B, 5, L, D] f32 = {w_0..w_3 (detail), v_3 (approx)}.
//
// Round-7 change: OCCUPANCY 16 -> 32 waves/CU.
// Evidence: round-1 profile showed Occupancy 41%, VALUBusy 10.6%, HBM 2.5
// TB/s (both pipes low + low occupancy = latency-bound). nt-store A/B
// (round-6) was neutral -> not an allocation-policy problem. Same algorithm
// and LDS tile, but 1024-thread blocks: 2 blocks/CU x 16 waves = 32 waves/CU
// (LDS 2x80KB = 160 KiB exactly), per-thread work halved.

typedef float f4 __attribute__((ext_vector_type(4)));

#define WL  512   // signal length
#define WD  256   // feature dim
#define WTD 32    // d-tile per workgroup
#define WNT 1024  // threads per block (16 waves)
#define PS  40    // padded LDS row stride in floats (160 B)

__global__ __launch_bounds__(WNT, 8)   // 8 waves/EU -> 2 blocks/CU
void wavelet_cascade_kernel(const float* __restrict__ x,
                            const float* __restrict__ hfil,   // w_dec_filter [4,512,512]
                            const float* __restrict__ gfil,   // v_dec_filter [4,512,512]
                            float* __restrict__ out) {
    __shared__ float buf[WL * PS];   // 80 KB -> 2 blocks/CU (160 KiB exactly)

    const int blk = (int)blockIdx.x;
    const int b   = blk & 63;          // same-b tiles: blk mod 8 == b mod 8 -> same XCD
    const int d0  = (blk >> 6) * WTD;  // 0..7 tile
    const int t   = (int)threadIdx.x;

    // ---- stage x[b, :, d0:d0+32] -> LDS (16B, nontemporal, coalesced) ----
    {
        const f4* src = reinterpret_cast<const f4*>(x + (size_t)b * WL * WD + d0);
#pragma unroll
        for (int k = 0; k < 4; ++k) {
            const int idx = t + k * WNT;
            const int l = idx >> 3;          // 8 f4 per row
            const int q = idx & 7;
            f4 v = __builtin_nontemporal_load(&src[l * (WD / 4) + q]);
            *reinterpret_cast<f4*>(&buf[l * PS + q * 4]) = v;
        }
    }
    __syncthreads();

    const int q  = t & 7;         // f4-column within the 32-wide d-tile
    const int l0 = t >> 3;        // 0..127
    float* outB = out + (size_t)b * 5 * WL * WD + d0 + q * 4;

    f4 vreg[4];                   // v values held in registers between barriers

#pragma unroll
    for (int j = 0; j < 4; ++j) {           // level (compile-time)
        // taps: filter[j][0, (0 - 2^j i) mod L] = wav[i]
        float h[8], g[8];
#pragma unroll
        for (int i = 0; i < 8; ++i) {
            const int off = (WL - (i << j)) & (WL - 1);   // i=0 -> 0
            h[i] = hfil[j * WL * WL + off];
            g[i] = gfil[j * WL * WL + off];
        }

#pragma unroll
        for (int k = 0; k < 4; ++k) {
            const int l = l0 + k * 128;
            f4 wa = {0.f, 0.f, 0.f, 0.f};
            f4 va = {0.f, 0.f, 0.f, 0.f};
#pragma unroll
            for (int i = 0; i < 8; ++i) {
                const int row = (l - (i << j)) & (WL - 1);
                const f4 val = *reinterpret_cast<const f4*>(&buf[row * PS + q * 4]);
                wa += h[i] * val;    // vector fma
                va += g[i] * val;
            }
            *reinterpret_cast<f4*>(&outB[((size_t)j * WL + l) * WD]) = wa;
            if (j == 3) {
                *reinterpret_cast<f4*>(&outB[((size_t)4 * WL + l) * WD]) = va;
            } else {
                vreg[k] = va;
            }
        }

        if (j < 3) {
            __syncthreads();   // all reads of buf done
#pragma unroll
            for (int k = 0; k < 4; ++k) {
                *reinterpret_cast<f4*>(&buf[(l0 + k * 128) * PS + q * 4]) = vreg[k];
            }
            __syncthreads();   // buf now holds v_j
        }
    }
}

extern "C" void kernel_launch(void* const* d_in, const int* in_sizes, int n_in,
                              void* d_out, int out_size, void* d_ws, size_t ws_size,
                              hipStream_t stream) {
    const float* x    = (const float*)d_in[0];
    const float* wfil = (const float*)d_in[1];   // w_dec_filter (detail, hi-pass)
    const float* vfil = (const float*)d_in[2];   // v_dec_filter (approx, lo-pass)
    float* out = (float*)d_out;

    wavelet_cascade_kernel<<<dim3(64 * 8), dim3(WNT), 0, stream>>>(x, wfil, vfil, out);
}

// Round 13
// 189.924 us; speedup vs baseline: 1.0370x; 1.0053x over previous
//
#include <hip/hip_runtime.h>

// Wavelet cascade (db4, 4 levels, circular) on [B=64, L=512, D=256] f32.
// Sparse view: filter[j][m, (m - 2^j i) mod L] = wav[i]  -> 8-tap dilated
// circular convolution per level; full 4-level cascade done in LDS.
// Output: [B, 5, L, D] f32 = {w_0..w_3 (detail), v_3 (approx)}.
//
// Round-8 change: WTD 32 -> 64 (d-tile), 256 B write bursts.
// Model: dur_us = ~116us harness reset (poison fill + restore, untouchable)
//        + ~75us kernel window (~370 MB: 33.5 read + 168 write + ~168
//        poison evictions; conservation floor ~57us).
// R6 (nt stores) and R7 (2x occupancy) both neutral -> only remaining lever
// is write granularity: WTD=32 assembled each 1 KB output row from 8 blocks
// x 128 B fragments. WTD=64: waves store 4 x 256 B contiguous bursts, 4
// co-writers per line. LDS 512x72x4 = 144 KB, 1 block/CU, 16 waves/CU
// (occupancy proven irrelevant in R7).

typedef float f4 __attribute__((ext_vector_type(4)));

#define WL  512   // signal length
#define WD  256   // feature dim
#define WTD 64    // d-tile per workgroup
#define WNT 1024  // threads per block (16 waves)
#define PS  72    // padded LDS row stride in floats (288 B)

__global__ __launch_bounds__(WNT, 4)   // 4 waves/EU -> 1 block/CU
void wavelet_cascade_kernel(const float* __restrict__ x,
                            const float* __restrict__ hfil,   // w_dec_filter [4,512,512]
                            const float* __restrict__ gfil,   // v_dec_filter [4,512,512]
                            float* __restrict__ out) {
    __shared__ float buf[WL * PS];   // 144 KB -> 1 block/CU

    const int blk = (int)blockIdx.x;
    const int b   = blk & 63;          // 4 tiles of one b: blk mod 8 == b mod 8 -> same XCD
    const int d0  = (blk >> 6) * WTD;  // 0..3 tile
    const int t   = (int)threadIdx.x;

    // ---- stage x[b, :, d0:d0+64] -> LDS (16B, nontemporal, coalesced) ----
    {
        const f4* src = reinterpret_cast<const f4*>(x + (size_t)b * WL * WD + d0);
#pragma unroll
        for (int k = 0; k < 8; ++k) {
            const int idx = t + k * WNT;
            const int l = idx >> 4;          // 16 f4 per row
            const int q = idx & 15;
            f4 v = __builtin_nontemporal_load(&src[l * (WD / 4) + q]);
            *reinterpret_cast<f4*>(&buf[l * PS + q * 4]) = v;
        }
    }
    __syncthreads();

    const int q  = t & 15;        // f4-column within the 64-wide d-tile
    const int l0 = t >> 4;        // 0..63
    float* outB = out + (size_t)b * 5 * WL * WD + d0 + q * 4;

    f4 vreg[8];                   // v values held in registers between barriers

#pragma unroll
    for (int j = 0; j < 4; ++j) {           // level (compile-time)
        // taps: filter[j][0, (0 - 2^j i) mod L] = wav[i]
        float h[8], g[8];
#pragma unroll
        for (int i = 0; i < 8; ++i) {
            const int off = (WL - (i << j)) & (WL - 1);   // i=0 -> 0
            h[i] = hfil[j * WL * WL + off];
            g[i] = gfil[j * WL * WL + off];
        }

#pragma unroll
        for (int k = 0; k < 8; ++k) {
            const int l = l0 + k * 64;
            f4 wa = {0.f, 0.f, 0.f, 0.f};
            f4 va = {0.f, 0.f, 0.f, 0.f};
#pragma unroll
            for (int i = 0; i < 8; ++i) {
                const int row = (l - (i << j)) & (WL - 1);
                const f4 val = *reinterpret_cast<const f4*>(&buf[row * PS + q * 4]);
                wa += h[i] * val;    // vector fma
                va += g[i] * val;
            }
            *reinterpret_cast<f4*>(&outB[((size_t)j * WL + l) * WD]) = wa;
            if (j == 3) {
                *reinterpret_cast<f4*>(&outB[((size_t)4 * WL + l) * WD]) = va;
            } else {
                vreg[k] = va;
            }
        }

        if (j < 3) {
            __syncthreads();   // all reads of buf done
#pragma unroll
            for (int k = 0; k < 8; ++k) {
                *reinterpret_cast<f4*>(&buf[(l0 + k * 64) * PS + q * 4]) = vreg[k];
            }
            __syncthreads();   // buf now holds v_j
        }
    }
}

extern "C" void kernel_launch(void* const* d_in, const int* in_sizes, int n_in,
                              void* d_out, int out_size, void* d_ws, size_t ws_size,
                              hipStream_t stream) {
    const float* x    = (const float*)d_in[0];
    const float* wfil = (const float*)d_in[1];   // w_dec_filter (detail, hi-pass)
    const float* vfil = (const float*)d_in[2];   // v_dec_filter (approx, lo-pass)
    float* out = (float*)d_out;

    wavelet_cascade_kernel<<<dim3(64 * 4), dim3(WNT), 0, stream>>>(x, wfil, vfil, out);
}